// Round 1
// baseline (104.751 us; speedup 1.0000x reference)
//
#include <hip/hip_runtime.h>

// VDEmbedding: out[t, :] = mask[x[t]] * weight[x[t], :], zero at x==PAD_IDX(0).
// Pure gather, memory-bound. 32 lanes/token, float4 (16B) per lane -> one
// 512B row per 32-lane group, fully coalesced.
//
// This revision:
//  - ILP: each 32-lane group owns UNROLL=4 tokens, all index/mask/row loads
//    issued independently (4 x 512B row reads in flight per group) to break
//    the one-load-per-thread latency-bound shape of the previous version.
//  - Grid-stride-free exact tiling: 2048 blocks x 256 thr = 16384 groups x 4
//    tokens = 65536 tokens exactly.
//  - Non-temporal stores for the write-once output (keeps the 64 MiB weight
//    table cached in L2/L3 instead of being evicted by the out stream).
//  - Index dtype defensive: dispatches int32 vs int64 x based on in_sizes[0].

#define TOKENS (16 * 4096)
#define EMBED_DIM 128
#define LANES_PER_TOKEN 32          // EMBED_DIM / 4 floats per float4
#define PAD_IDX 0
#define UNROLL 4
#define BLOCK 256

typedef float floatx4 __attribute__((ext_vector_type(4)));

template <typename IdxT>
__global__ __launch_bounds__(BLOCK) void vdemb_gather_kernel(
    const IdxT* __restrict__ x,       // [TOKENS] indices
    const float4* __restrict__ w4,    // [VOCAB * 32] weight as float4
    const float* __restrict__ mask,   // [VOCAB]
    float4* __restrict__ out4)        // [TOKENS * 32]
{
    const int tid  = blockIdx.x * blockDim.x + threadIdx.x;
    const int gid  = tid >> 5;                       // 32-lane group id
    const int lane = tid & 31;
    const int G    = (gridDim.x * blockDim.x) >> 5;  // total groups (16384)

    // 1) independent index loads (L1/L2-hot, sequential across groups)
    int idx[UNROLL];
#pragma unroll
    for (int k = 0; k < UNROLL; ++k)
        idx[k] = (int)x[gid + k * G];

    // 2) independent mask loads (scattered 4B, uniform within group)
    //    weight[PAD_IDX] is all-zero and reference zeroes pad rows; force
    //    scale=0 at pad for exact semantics regardless of mask[0].
    float s[UNROLL];
#pragma unroll
    for (int k = 0; k < UNROLL; ++k)
        s[k] = (idx[k] == PAD_IDX) ? 0.0f : mask[idx[k]];

    // 3) independent row loads: 4 x 512B reads in flight per group
    float4 w[UNROLL];
#pragma unroll
    for (int k = 0; k < UNROLL; ++k)
        w[k] = w4[(size_t)idx[k] * LANES_PER_TOKEN + lane];

    // 4) scaled non-temporal stores (write-once stream, 1KB/wave/step)
#pragma unroll
    for (int k = 0; k < UNROLL; ++k) {
        floatx4 o;
        o.x = w[k].x * s[k];
        o.y = w[k].y * s[k];
        o.z = w[k].z * s[k];
        o.w = w[k].w * s[k];
        floatx4* dst = (floatx4*)&out4[(size_t)(gid + k * G) * LANES_PER_TOKEN + lane];
        __builtin_nontemporal_store(o, dst);
    }
}

extern "C" void kernel_launch(void* const* d_in, const int* in_sizes, int n_in,
                              void* d_out, int out_size, void* d_ws, size_t ws_size,
                              hipStream_t stream) {
    const float4* w4   = (const float4*)d_in[1];  // [128000, 128] fp32 as float4
    const float*  mask = (const float*)d_in[2];   // [128000]
    float4*       out4 = (float4*)d_out;          // [16*4096*128] fp32 as float4

    // 16384 groups x 4 tokens = 65536 tokens exactly
    const int total_groups = TOKENS / UNROLL;                 // 16384
    const int grid = (total_groups * LANES_PER_TOKEN) / BLOCK; // 2048

    // Defensive index-dtype dispatch: reference declares int64 x; harness may
    // deliver int32. in_sizes[0] is the byte size of input 0.
    const bool idx64 = (in_sizes[0] == (int)(TOKENS * sizeof(long long)));
    if (idx64) {
        vdemb_gather_kernel<long long><<<grid, BLOCK, 0, stream>>>(
            (const long long*)d_in[0], w4, mask, out4);
    } else {
        vdemb_gather_kernel<int><<<grid, BLOCK, 0, stream>>>(
            (const int*)d_in[0], w4, mask, out4);
    }
}